// Round 1
// baseline (1303.399 us; speedup 1.0000x reference)
//
#include <hip/hip_runtime.h>
#include <math.h>

#define BWIN  4096
#define C     128
#define NTOK  49
#define NP    56     // padded token count (8 groups x 7)
#define O3    384
#define HEADS 4
#define HD    32
#define SCALE 0.17677669529663687f   // 1/sqrt(32)

// ---- LDS arena (float offsets) ----
// qs : [384][56]  @ 0       (21504 floats)  qkv output, live through PV (v rows)
// xs : [128][56]  @ 21504   (7168)          x tile, dead after qkv
// ws : [16][388]  @ 28672   (6208)          qkv_w chunk, dead after qkv
// S  : [4][49][53]@ 21504   (10388)         scores/probs, overlaps xs+ws
// ao : [56][132]  @ 0       (7392)          attn out, overlaps dead q/k rows
// pw : [64][132]  @ 21504   (8448)          proj_w chunk, overlaps dead S
#define OFF_QS 0
#define OFF_XS 21504
#define OFF_WS 28672
#define OFF_S  21504
#define OFF_AO 0
#define OFF_PW 21504
#define ARENA_FLOATS 34880   // 139520 bytes

__global__ __launch_bounds__(256)
void win_attn_kernel(const float* __restrict__ x, const float* __restrict__ mask,
                     const float* __restrict__ qkv_w, const float* __restrict__ qkv_b,
                     const float* __restrict__ proj_w, const float* __restrict__ proj_b,
                     const float* __restrict__ bias_table, float* __restrict__ out)
{
    extern __shared__ float lds[];
    const int b   = blockIdx.x;
    const int tid = threadIdx.x;

    float* qs = lds + OFF_QS;
    float* xs = lds + OFF_XS;
    float* ws = lds + OFF_WS;

    const float* xb = x + (size_t)b * (C * NTOK);

    // ---------- phase 1: x -> LDS xs[c][n] (zero padded n) ----------
    for (int i = tid; i < C * NP; i += 256) xs[i] = 0.0f;
    __syncthreads();
    for (int i = tid; i < C * NTOK; i += 256) {
        int c = i / NTOK, n = i - c * NTOK;
        xs[c * NP + n] = xb[i];
    }
    __syncthreads();

    // ---------- phase 2: qkv GEMM -> qs[o][n] ----------
    {
        const int tx = tid & 31;   // o = tx*12 + j
        const int ty = tid >> 5;   // n = ty*7 + i
        float acc[7][12];
        #pragma unroll
        for (int i = 0; i < 7; ++i) {
            #pragma unroll
            for (int j = 0; j < 12; ++j) acc[i][j] = 0.0f;
        }
        for (int cb = 0; cb < C; cb += 16) {
            // stage ws[cc][o] = qkv_w[o][cb+cc]
            for (int i = tid; i < 16 * O3; i += 256) {
                int o = i >> 4, cc = i & 15;
                ws[cc * 388 + o] = qkv_w[o * C + cb + cc];
            }
            __syncthreads();
            #pragma unroll
            for (int cc = 0; cc < 16; ++cc) {
                float xv[7], wv[12];
                #pragma unroll
                for (int i = 0; i < 7; ++i) xv[i] = xs[(cb + cc) * NP + ty * 7 + i];
                #pragma unroll
                for (int j = 0; j < 12; ++j) wv[j] = ws[cc * 388 + tx * 12 + j];
                #pragma unroll
                for (int i = 0; i < 7; ++i) {
                    #pragma unroll
                    for (int j = 0; j < 12; ++j) acc[i][j] += xv[i] * wv[j];
                }
            }
            __syncthreads();
        }
        #pragma unroll
        for (int j = 0; j < 12; ++j) {
            int o = tx * 12 + j;
            float bo = qkv_b[o];
            #pragma unroll
            for (int i = 0; i < 7; ++i) {
                int n = ty * 7 + i;
                if (n < NTOK) qs[o * NP + n] = acc[i][j] + bo;
            }
        }
    }
    __syncthreads();

    // ---------- phase 3: attention, one wave per head ----------
    const int h    = tid >> 6;
    const int lane = tid & 63;
    float* Sh = lds + OFF_S + h * (NTOK * 53);
    const float* q_ = qs + (h * HD) * NP;
    const float* k_ = qs + (C + h * HD) * NP;
    const float* v_ = qs + (2 * C + h * HD) * NP;

    // QK^T (7x7 micro-tile per lane, lanes 0..48) + scale + rel-bias + mask
    if (lane < 49) {
        const int gn = lane / 7, gm = lane - (lane / 7) * 7;
        float sa[7][7];
        #pragma unroll
        for (int i = 0; i < 7; ++i) {
            #pragma unroll
            for (int j = 0; j < 7; ++j) sa[i][j] = 0.0f;
        }
        #pragma unroll 4
        for (int d = 0; d < HD; ++d) {
            float qv[7], kv[7];
            #pragma unroll
            for (int i = 0; i < 7; ++i) qv[i] = q_[d * NP + gn * 7 + i];
            #pragma unroll
            for (int j = 0; j < 7; ++j) kv[j] = k_[d * NP + gm * 7 + j];
            #pragma unroll
            for (int i = 0; i < 7; ++i) {
                #pragma unroll
                for (int j = 0; j < 7; ++j) sa[i][j] += qv[i] * kv[j];
            }
        }
        const int wi = b & 63;   // tile(mask, B/nW) -> mask[b % 64]
        const float* mrow = mask + (size_t)wi * (NTOK * NTOK);
        #pragma unroll
        for (int i = 0; i < 7; ++i) {
            int n = gn * 7 + i, yn = n / 7, xn = n - yn * 7;
            #pragma unroll
            for (int j = 0; j < 7; ++j) {
                int m = gm * 7 + j, ym = m / 7, xm = m - ym * 7;
                int ridx = (yn - ym + 6) * 13 + (xn - xm + 6);
                Sh[n * 53 + m] = sa[i][j] * SCALE + bias_table[ridx * HEADS + h]
                               + mrow[n * NTOK + m];
            }
        }
    }
    __syncthreads();

    // softmax over m, one row per lane
    if (lane < 49) {
        float* row = Sh + lane * 53;
        float mx = row[0];
        #pragma unroll
        for (int m = 1; m < NTOK; ++m) mx = fmaxf(mx, row[m]);
        float sum = 0.0f;
        #pragma unroll
        for (int m = 0; m < NTOK; ++m) { float e = __expf(row[m] - mx); row[m] = e; sum += e; }
        float rs = 1.0f / sum;
        #pragma unroll
        for (int m = 0; m < NTOK; ++m) row[m] *= rs;
    }
    __syncthreads();

    // PV: lanes 0..55, micro-tile 7n x 4d -> ao[n][h*32+d]
    float* ao = lds + OFF_AO;
    if (lane < 56) {
        const int ng = lane >> 3, dg = lane & 7;
        float pa[7][4];
        #pragma unroll
        for (int i = 0; i < 7; ++i) {
            #pragma unroll
            for (int j = 0; j < 4; ++j) pa[i][j] = 0.0f;
        }
        #pragma unroll 7
        for (int m = 0; m < NTOK; ++m) {
            float pvv[7], vv[4];
            #pragma unroll
            for (int i = 0; i < 7; ++i) pvv[i] = Sh[(ng * 7 + i) * 53 + m];
            #pragma unroll
            for (int j = 0; j < 4; ++j) vv[j] = v_[(dg * 4 + j) * NP + m];
            #pragma unroll
            for (int i = 0; i < 7; ++i) {
                #pragma unroll
                for (int j = 0; j < 4; ++j) pa[i][j] += pvv[i] * vv[j];
            }
        }
        #pragma unroll
        for (int i = 0; i < 7; ++i) {
            #pragma unroll
            for (int j = 0; j < 4; ++j)
                ao[(ng * 7 + i) * 132 + h * HD + dg * 4 + j] = pa[i][j];
        }
    }
    // zero ao pad rows 49..55 (proj reads them)
    for (int i = tid; i < 7 * 132; i += 256) ao[49 * 132 + i] = 0.0f;
    __syncthreads();

    // ---------- phase 4: proj GEMM + bias -> out (NCHW) ----------
    float* pw = lds + OFF_PW;
    {
        const int tco = tid & 31;  // co = tco*4 + j
        const int tn  = tid >> 5;  // n  = tn*7 + i
        float pacc[7][4];
        #pragma unroll
        for (int i = 0; i < 7; ++i) {
            #pragma unroll
            for (int j = 0; j < 4; ++j) pacc[i][j] = 0.0f;
        }
        for (int cb = 0; cb < C; cb += 64) {
            // stage pw[cc][co] = proj_w[co][cb+cc], coalesced over cc
            for (int i = tid; i < 64 * C; i += 256) {
                int co = i >> 6, cc = i & 63;
                pw[cc * 132 + co] = proj_w[co * C + cb + cc];
            }
            __syncthreads();
            #pragma unroll
            for (int cc = 0; cc < 64; ++cc) {
                float av[7], wv[4];
                #pragma unroll
                for (int i = 0; i < 7; ++i) av[i] = ao[(tn * 7 + i) * 132 + cb + cc];
                #pragma unroll
                for (int j = 0; j < 4; ++j) wv[j] = pw[cc * 132 + tco * 4 + j];
                #pragma unroll
                for (int i = 0; i < 7; ++i) {
                    #pragma unroll
                    for (int j = 0; j < 4; ++j) pacc[i][j] += av[i] * wv[j];
                }
            }
            __syncthreads();
        }
        float* ob = out + (size_t)b * (C * NTOK);
        #pragma unroll
        for (int j = 0; j < 4; ++j) {
            int co = tco * 4 + j;
            float pb = proj_b[co];
            #pragma unroll
            for (int i = 0; i < 7; ++i) {
                int n = tn * 7 + i;
                if (n < NTOK) ob[co * NTOK + n] = pacc[i][j] + pb;
            }
        }
    }
}

extern "C" void kernel_launch(void* const* d_in, const int* in_sizes, int n_in,
                              void* d_out, int out_size, void* d_ws, size_t ws_size,
                              hipStream_t stream) {
    const float* x      = (const float*)d_in[0];
    const float* mask   = (const float*)d_in[1];
    const float* qkv_w  = (const float*)d_in[2];
    const float* qkv_b  = (const float*)d_in[3];
    const float* proj_w = (const float*)d_in[4];
    const float* proj_b = (const float*)d_in[5];
    const float* btab   = (const float*)d_in[6];
    float* o = (float*)d_out;

    const size_t lds_bytes = ARENA_FLOATS * sizeof(float);
    hipFuncSetAttribute(reinterpret_cast<const void*>(win_attn_kernel),
                        hipFuncAttributeMaxDynamicSharedMemorySize, (int)lds_bytes);
    win_attn_kernel<<<BWIN, 256, lds_bytes, stream>>>(x, mask, qkv_w, qkv_b,
                                                      proj_w, proj_b, btab, o);
}

// Round 3
// 173.563 us; speedup vs baseline: 7.5096x; 7.5096x over previous
//
#include <hip/hip_runtime.h>

typedef __attribute__((ext_vector_type(8))) short short8;
typedef __attribute__((ext_vector_type(4))) float f32x4;
typedef __attribute__((ext_vector_type(4))) unsigned short bfu4;

#define MFMA(a, b, c) __builtin_amdgcn_mfma_f32_16x16x32_bf16((a), (b), (c), 0, 0, 0)

__device__ __forceinline__ unsigned short f2bf(float f) {
    union { float f; unsigned u; } v; v.f = f;
    unsigned r = v.u + 0x7fffu + ((v.u >> 16) & 1u);
    return (unsigned short)(r >> 16);
}

// ---------------- prep: weights -> fragment-linear bf16 in d_ws ----------------
// layout (bf16 elements): [0,49152): qkv frags  frag=( (mt*4+ks)*64 + l ), elem j
//                         [49152,65536): proj frags (mt 0..7)
__global__ __launch_bounds__(256)
void prep_kernel(const float* __restrict__ qkv_w, const float* __restrict__ proj_w,
                 unsigned short* __restrict__ wf)
{
    int id = blockIdx.x * 256 + threadIdx.x;          // 0..65535
    int j  = id & 7;
    int l  = (id >> 3) & 63;
    int ks = (id >> 9) & 3;
    int row16 = l & 15;
    int kk = ks * 32 + ((l >> 4) << 3) + j;
    if (id < 49152) {
        int mt = id >> 11;                            // 0..23
        wf[id] = f2bf(qkv_w[(mt * 16 + row16) * 128 + kk]);
    } else {
        int mt = (id - 49152) >> 11;                  // 0..7
        wf[id] = f2bf(proj_w[(mt * 16 + row16) * 128 + kk]);
    }
}

// ---------------- main fused kernel: one block (256 thr / 4 waves) per window ----------------
// LDS arena (64KB), byte offsets:
//  xsT [64 n][128 c] bf16 @0      (16KB)  swz: ^((n&7)<<4), row 256B
//  qkT [4 h][64 n][64] bf16 @16K  (32KB)  q cols 0..31, k cols 32..63; swz ^((n&7)<<4), row 128B
//  Vt  [4 h][32 d][64 m] bf16 @48K(16KB)  swz ^((d&7)<<4), row 128B
//  P   [4 h][64 n][64 m] bf16 @0  (32KB)  overlaps xsT+qkT[0..1] (dead after barrier 3)
//  aoT [64 n][128 c] bf16 @32K    (16KB)  overlaps qkT[2..3]
#define XS 0
#define QKO 16384
#define VTO 49152
#define PPO 0
#define AOO 32768
#define LDS_BYTES 65536
#define SCALE 0.17677669529663687f

__global__ __launch_bounds__(256, 2)
void win_attn_mfma(const float* __restrict__ x, const float* __restrict__ mask,
                   const float* __restrict__ qkv_b, const float* __restrict__ proj_b,
                   const float* __restrict__ bt, const unsigned short* __restrict__ wf,
                   float* __restrict__ out)
{
    extern __shared__ char smem[];
    const int b = blockIdx.x, tid = threadIdx.x;
    const int w = tid >> 6, l = tid & 63, g = l >> 4, lr = l & 15;

    // ---- stage x -> xsT[n][c] bf16 (transposed, swizzled, zero-padded rows 49..63) ----
    const float* xb = x + (size_t)b * 6272;
    for (int r = tid; r < 6272; r += 256) {
        int c = (int)(((unsigned)r * 21400u) >> 20);   // r / 49
        int n = r - c * 49;
        int byte = n * 256 + ((c * 2) ^ ((n & 7) << 4));
        *(unsigned short*)(smem + XS + byte) = f2bf(xb[r]);
    }
    for (int i = tid; i < 1920; i += 256) {            // pad rows
        int n = 49 + (i >> 7), c = i & 127;
        int byte = n * 256 + ((c * 2) ^ ((n & 7) << 4));
        *(unsigned short*)(smem + XS + byte) = 0;
    }
    __syncthreads();

    const short8* wfa = (const short8*)wf;

    // ---- phase A: qkv = W(384x128) * x(128x64), wave w owns o in [w*96, w*96+96) ----
    {
        f32x4 acc[6][4];
        #pragma unroll
        for (int mt = 0; mt < 6; ++mt)
            #pragma unroll
            for (int nt = 0; nt < 4; ++nt) acc[mt][nt] = (f32x4){0.f, 0.f, 0.f, 0.f};

        #pragma unroll
        for (int ks = 0; ks < 4; ++ks) {
            short8 aF[6], bF[4];
            #pragma unroll
            for (int mt = 0; mt < 6; ++mt)
                aF[mt] = wfa[((w * 6 + mt) * 4 + ks) * 64 + l];
            #pragma unroll
            for (int nt = 0; nt < 4; ++nt) {
                int n = nt * 16 + lr;
                int byte = n * 256 + (((ks * 32 + g * 8) * 2) ^ ((n & 7) << 4));
                bF[nt] = *(const short8*)(smem + XS + byte);
            }
            #pragma unroll
            for (int mt = 0; mt < 6; ++mt)
                #pragma unroll
                for (int nt = 0; nt < 4; ++nt)
                    acc[mt][nt] = MFMA(aF[mt], bF[nt], acc[mt][nt]);
        }

        #pragma unroll
        for (int mt = 0; mt < 6; ++mt) {
            int o0 = w * 96 + mt * 16;
            f32x4 bias = *(const f32x4*)(qkv_b + o0 + g * 4);
            #pragma unroll
            for (int nt = 0; nt < 4; ++nt) acc[mt][nt] += bias;

            if (o0 < 128) {                       // q (scale folded in)
                int hh = o0 >> 5, dl = (o0 & 31) + g * 4;
                #pragma unroll
                for (int nt = 0; nt < 4; ++nt) {
                    int n = nt * 16 + lr;
                    bfu4 u;
                    #pragma unroll
                    for (int r2 = 0; r2 < 4; ++r2) u[r2] = f2bf(acc[mt][nt][r2] * SCALE);
                    int byte = hh * 8192 + n * 128 + ((dl * 2) ^ ((n & 7) << 4));
                    *(bfu4*)(smem + QKO + byte) = u;
                }
            } else if (o0 < 256) {                // k
                int o2 = o0 - 128, hh = o2 >> 5, dl = (o2 & 31) + g * 4;
                #pragma unroll
                for (int nt = 0; nt < 4; ++nt) {
                    int n = nt * 16 + lr;
                    bfu4 u;
                    #pragma unroll
                    for (int r2 = 0; r2 < 4; ++r2) u[r2] = f2bf(acc[mt][nt][r2]);
                    int byte = hh * 8192 + n * 128 + ((64 + dl * 2) ^ ((n & 7) << 4));
                    *(bfu4*)(smem + QKO + byte) = u;
                }
            } else {                              // v -> Vt[d][m] (transposed)
                int o2 = o0 - 256, hh = o2 >> 5, dl = (o2 & 31) + g * 4;
                #pragma unroll
                for (int nt = 0; nt < 4; ++nt) {
                    int m = nt * 16 + lr;
                    #pragma unroll
                    for (int r2 = 0; r2 < 4; ++r2) {
                        int d = dl + r2;
                        int byte = hh * 4096 + d * 128 + ((m * 2) ^ ((d & 7) << 4));
                        *(unsigned short*)(smem + VTO + byte) = f2bf(acc[mt][nt][r2]);
                    }
                }
            }
        }
    }
    __syncthreads();

    // ---- phase B: attention, wave w = head h ----
    const int h = w, wi = b & 63;
    f32x4 S[4][4];

    // C-init = mask + rel_bias (pad m>=49 -> -1e30 so softmax needs no masking)
    {
        int pm[4], mc[4]; bool mv[4];
        #pragma unroll
        for (int nt = 0; nt < 4; ++nt) {
            int m = nt * 16 + lr;
            int m_c = m > 48 ? 48 : m;
            int ym = (m_c * 147) >> 10, xm = m_c - ym * 7;
            pm[nt] = ym * 13 + xm; mc[nt] = m_c; mv[nt] = (m < 49);
        }
        const float* mrow = mask + (size_t)wi * 2401;
        #pragma unroll
        for (int mt = 0; mt < 4; ++mt) {
            #pragma unroll
            for (int r2 = 0; r2 < 4; ++r2) {
                int n = mt * 16 + g * 4 + r2;
                int n_c = n > 48 ? 48 : n;
                int yn = (n_c * 147) >> 10, xn = n_c - yn * 7;
                int pn = yn * 13 + xn;
                const float* mr2 = mrow + n_c * 49;
                #pragma unroll
                for (int nt = 0; nt < 4; ++nt) {
                    S[mt][nt][r2] = mv[nt]
                        ? (mr2[mc[nt]] + bt[(pn - pm[nt] + 84) * 4 + h])
                        : -1e30f;
                }
            }
        }
    }

    // QK^T: S += q * k^T (K=32, one k-step)
    {
        short8 qF[4], kF[4];
        #pragma unroll
        for (int t = 0; t < 4; ++t) {
            int n = t * 16 + lr;
            int rb2 = h * 8192 + n * 128, sw = (n & 7) << 4;
            qF[t] = *(const short8*)(smem + QKO + rb2 + ((g * 16) ^ sw));
            kF[t] = *(const short8*)(smem + QKO + rb2 + ((64 + g * 16) ^ sw));
        }
        #pragma unroll
        for (int mt = 0; mt < 4; ++mt)
            #pragma unroll
            for (int nt = 0; nt < 4; ++nt)
                S[mt][nt] = MFMA(qF[mt], kF[nt], S[mt][nt]);
    }

    // softmax over m (cols spread across lanes lr and tiles nt)
    #pragma unroll
    for (int mt = 0; mt < 4; ++mt) {
        f32x4 mx = S[mt][0];
        #pragma unroll
        for (int nt = 1; nt < 4; ++nt)
            #pragma unroll
            for (int r2 = 0; r2 < 4; ++r2) mx[r2] = fmaxf(mx[r2], S[mt][nt][r2]);
        #pragma unroll
        for (int r2 = 0; r2 < 4; ++r2) {
            float v2 = mx[r2];
            v2 = fmaxf(v2, __shfl_xor(v2, 1));
            v2 = fmaxf(v2, __shfl_xor(v2, 2));
            v2 = fmaxf(v2, __shfl_xor(v2, 4));
            v2 = fmaxf(v2, __shfl_xor(v2, 8));
            mx[r2] = v2;
        }
        f32x4 sum = (f32x4){0.f, 0.f, 0.f, 0.f};
        #pragma unroll
        for (int nt = 0; nt < 4; ++nt)
            #pragma unroll
            for (int r2 = 0; r2 < 4; ++r2) {
                float e = __expf(S[mt][nt][r2] - mx[r2]);
                S[mt][nt][r2] = e; sum[r2] += e;
            }
        #pragma unroll
        for (int r2 = 0; r2 < 4; ++r2) {
            float s2 = sum[r2];
            s2 += __shfl_xor(s2, 1);
            s2 += __shfl_xor(s2, 2);
            s2 += __shfl_xor(s2, 4);
            s2 += __shfl_xor(s2, 8);
            sum[r2] = 1.0f / s2;
        }
        #pragma unroll
        for (int nt = 0; nt < 4; ++nt)
            #pragma unroll
            for (int r2 = 0; r2 < 4; ++r2) S[mt][nt][r2] *= sum[r2];
    }
    __syncthreads();   // barrier 3: qkT dead everywhere; P/aoT regions now writable

    // P -> LDS (bf16)
    #pragma unroll
    for (int mt = 0; mt < 4; ++mt)
        #pragma unroll
        for (int r2 = 0; r2 < 4; ++r2) {
            int n = mt * 16 + g * 4 + r2;
            int rowb = h * 8192 + n * 128, sw = (n & 7) << 4;
            #pragma unroll
            for (int nt = 0; nt < 4; ++nt) {
                int m = nt * 16 + lr;
                *(unsigned short*)(smem + PPO + rowb + ((m * 2) ^ sw)) = f2bf(S[mt][nt][r2]);
            }
        }

    // PV: O = P(64x64) * V(64x32)
    f32x4 O[4][2];
    #pragma unroll
    for (int mt = 0; mt < 4; ++mt)
        #pragma unroll
        for (int nt2 = 0; nt2 < 2; ++nt2) O[mt][nt2] = (f32x4){0.f, 0.f, 0.f, 0.f};
    #pragma unroll
    for (int ks2 = 0; ks2 < 2; ++ks2) {
        short8 pF[4], vF[2];
        #pragma unroll
        for (int mt = 0; mt < 4; ++mt) {
            int n = mt * 16 + lr;
            pF[mt] = *(const short8*)(smem + PPO + h * 8192 + n * 128 +
                                      ((ks2 * 64 + g * 16) ^ ((n & 7) << 4)));
        }
        #pragma unroll
        for (int nt2 = 0; nt2 < 2; ++nt2) {
            int d = nt2 * 16 + lr;
            vF[nt2] = *(const short8*)(smem + VTO + h * 4096 + d * 128 +
                                       ((ks2 * 64 + g * 16) ^ ((d & 7) << 4)));
        }
        #pragma unroll
        for (int mt = 0; mt < 4; ++mt)
            #pragma unroll
            for (int nt2 = 0; nt2 < 2; ++nt2)
                O[mt][nt2] = MFMA(pF[mt], vF[nt2], O[mt][nt2]);
    }
    // attn out -> aoT[n][c]
    #pragma unroll
    for (int mt = 0; mt < 4; ++mt)
        #pragma unroll
        for (int nt2 = 0; nt2 < 2; ++nt2)
            #pragma unroll
            for (int r2 = 0; r2 < 4; ++r2) {
                int n = mt * 16 + g * 4 + r2;
                int c = h * 32 + nt2 * 16 + lr;
                *(unsigned short*)(smem + AOO + n * 256 + ((c * 2) ^ ((n & 7) << 4))) =
                    f2bf(O[mt][nt2][r2]);
            }
    __syncthreads();   // barrier 4

    // ---- phase C: proj, wave w owns co in [w*32, w*32+32) ----
    f32x4 Pa[4][2];
    #pragma unroll
    for (int mt = 0; mt < 4; ++mt)
        #pragma unroll
        for (int ct = 0; ct < 2; ++ct) Pa[mt][ct] = (f32x4){0.f, 0.f, 0.f, 0.f};
    #pragma unroll
    for (int ks = 0; ks < 4; ++ks) {
        short8 aF[4], bF[2];
        #pragma unroll
        for (int mt = 0; mt < 4; ++mt) {
            int n = mt * 16 + lr;
            aF[mt] = *(const short8*)(smem + AOO + n * 256 +
                                      (((ks * 32 + g * 8) * 2) ^ ((n & 7) << 4)));
        }
        #pragma unroll
        for (int ct = 0; ct < 2; ++ct)
            bF[ct] = wfa[6144 + ((w * 2 + ct) * 4 + ks) * 64 + l];
        #pragma unroll
        for (int mt = 0; mt < 4; ++mt)
            #pragma unroll
            for (int ct = 0; ct < 2; ++ct)
                Pa[mt][ct] = MFMA(aF[mt], bF[ct], Pa[mt][ct]);
    }
    float* ob = out + (size_t)b * 6272;
    #pragma unroll
    for (int ct = 0; ct < 2; ++ct) {
        int co = (w * 2 + ct) * 16 + lr;
        float pb2 = proj_b[co];
        #pragma unroll
        for (int mt = 0; mt < 4; ++mt) {
            int n0 = mt * 16 + g * 4;
            if (mt < 3) {
                #pragma unroll
                for (int r2 = 0; r2 < 4; ++r2)
                    ob[co * 49 + n0 + r2] = Pa[mt][ct][r2] + pb2;
            } else if (g == 0) {
                ob[co * 49 + 48] = Pa[3][ct][0] + pb2;
            }
        }
    }
}

extern "C" void kernel_launch(void* const* d_in, const int* in_sizes, int n_in,
                              void* d_out, int out_size, void* d_ws, size_t ws_size,
                              hipStream_t stream) {
    const float* x      = (const float*)d_in[0];
    const float* mask   = (const float*)d_in[1];
    const float* qkv_w  = (const float*)d_in[2];
    const float* qkv_b  = (const float*)d_in[3];
    const float* proj_w = (const float*)d_in[4];
    const float* proj_b = (const float*)d_in[5];
    const float* btab   = (const float*)d_in[6];
    float* o = (float*)d_out;
    unsigned short* wf = (unsigned short*)d_ws;

    prep_kernel<<<256, 256, 0, stream>>>(qkv_w, proj_w, wf);

    hipFuncSetAttribute(reinterpret_cast<const void*>(win_attn_mfma),
                        hipFuncAttributeMaxDynamicSharedMemorySize, LDS_BYTES);
    win_attn_mfma<<<4096, 256, LDS_BYTES, stream>>>(x, mask, qkv_b, proj_b, btab, wf, o);
}